// Round 11
// baseline (348.297 us; speedup 1.0000x reference)
//
#include <hip/hip_runtime.h>
#include <hip/hip_bf16.h>
#include <math.h>

// v11: two-kernel restructure.
// prep: x fp32 -> f16 + hash-encode -> H0 f16[B][832] (pure stream+gather).
// fused_mlp: 128-row x 16-wave blocks; L0 = uniform 13-step BK64 loop with
// global_load_lds(16B) staging (linear LDS dest, inverse-swizzled global
// source, swizzled read); K12/L3 as before but weight-L2 traffic halved.

#define T_SIZE 524288   // 2^19
#define T_MASK (T_SIZE - 1)

typedef _Float16 f16;
typedef _Float16 f16x8 __attribute__((ext_vector_type(8)));
typedef _Float16 f16x4 __attribute__((ext_vector_type(4)));
typedef float f32x4 __attribute__((ext_vector_type(4)));

struct Scales { float s[16]; };

#define GLD16(gsrc, ldst) __builtin_amdgcn_global_load_lds( \
    (const __attribute__((address_space(1))) void*)(gsrc),  \
    (__attribute__((address_space(3))) void*)(ldst), 16, 0, 0)

// ---------------- weight -> fragment-linear f16 ----------------
// Wf[frag][lane][8]: frag = nblk*(K/32)+ks32; (lane,j) = W[ks32*32+(lane>>4)*8+j][nblk*16+(lane&15)]
__global__ void wfrag(const float* __restrict__ W, f16* __restrict__ Wf, int K, int N) {
  int tid = blockIdx.x * 256 + threadIdx.x;
  int lane = tid & 63, frag = tid >> 6;
  int KS = K >> 5;
  int nblk = frag / KS, ks = frag - nblk * KS;
  if (nblk * 16 >= N) return;
  int n = nblk * 16 + (lane & 15);
  int kb = ks * 32 + (lane >> 4) * 8;
  f16x8 v;
#pragma unroll
  for (int j = 0; j < 8; ++j) v[j] = (f16)W[(size_t)(kb + j) * N + n];
  *(f16x8*)(Wf + (size_t)frag * 512 + lane * 8) = v;
}

__device__ __forceinline__ float silu_f(float v) {
  return v * __builtin_amdgcn_rcpf(1.f + __expf(-v));
}

__device__ __forceinline__ f16x8 cvt8(f32x4 a, f32x4 b) {
  return (f16x8){ (f16)a.x, (f16)a.y, (f16)a.z, (f16)a.w,
                  (f16)b.x, (f16)b.y, (f16)b.z, (f16)b.w };
}

// ---------------- prep: H0[b][832] = [f16(x) | enc] ----------------
// 256 threads = 32 rows x 8; thread (row, c8): x cols {j*64 + c8*8}, levels 2c8, 2c8+1.
__global__ __launch_bounds__(256) void prep(
    const float* __restrict__ x, const float* __restrict__ t,
    const float* __restrict__ cond, const float* __restrict__ tables,
    f16* __restrict__ H0, Scales scl) {
  const int row = blockIdx.x * 32 + (threadIdx.x >> 3);
  const int c8 = threadIdx.x & 7;
  const float* xr = x + (size_t)row * 768;
  f16* hr = H0 + (size_t)row * 832;

  // enc: batched addr-gen -> loads -> accumulate
  {
    float c0 = cond[2 * row], c1 = cond[2 * row + 1], c2 = t[row];
    unsigned idx[2][8];
    float    wcw[2][8];
#pragma unroll
    for (int d = 0; d < 2; ++d) {
      int l = c8 * 2 + d;
      float s = scl.s[l];
      float xf0 = c0 * s, xf1 = c1 * s, xf2 = c2 * s;
      float xl0 = floorf(xf0), xl1 = floorf(xf1), xl2 = floorf(xf2);
      float w0 = xf0 - xl0, w1 = xf1 - xl1, w2 = xf2 - xl2;
      unsigned xi0 = (unsigned)xl0, xi1 = (unsigned)xl1, xi2 = (unsigned)xl2;
      unsigned h0 = xi0, h1 = xi1 * 2654435761u, h2 = xi2 * 805459861u;
      unsigned g0 = xi0 + 1u, g1 = (xi1 + 1u) * 2654435761u, g2 = (xi2 + 1u) * 805459861u;
#pragma unroll
      for (int c = 0; c < 8; ++c) {
        unsigned ax = (c >> 2) & 1u, ay = (c >> 1) & 1u, az = c & 1u;
        unsigned hh = (ax ? g0 : h0) ^ (ay ? g1 : h1) ^ (az ? g2 : h2);
        idx[d][c] = hh & T_MASK;
        wcw[d][c] = (ax ? w0 : 1.f - w0) * (ay ? w1 : 1.f - w1) * (az ? w2 : 1.f - w2);
      }
    }
    const f32x4* tl0 = (const f32x4*)tables + (size_t)(c8 * 2) * T_SIZE;
    f32x4 fv[2][8];
#pragma unroll
    for (int d = 0; d < 2; ++d)
#pragma unroll
      for (int c = 0; c < 8; ++c)
        fv[d][c] = tl0[(size_t)d * T_SIZE + idx[d][c]];
    f16x8 er;
#pragma unroll
    for (int d = 0; d < 2; ++d) {
      float a0 = 0.f, a1 = 0.f, a2 = 0.f, a3 = 0.f;
#pragma unroll
      for (int c = 0; c < 8; ++c) {
        a0 += wcw[d][c] * fv[d][c].x; a1 += wcw[d][c] * fv[d][c].y;
        a2 += wcw[d][c] * fv[d][c].z; a3 += wcw[d][c] * fv[d][c].w;
      }
      er[d * 4 + 0] = (f16)a0; er[d * 4 + 1] = (f16)a1;
      er[d * 4 + 2] = (f16)a2; er[d * 4 + 3] = (f16)a3;
    }
    *(f16x8*)(hr + 768 + c8 * 8) = er;
  }

  // x convert (coalesced within row-group)
#pragma unroll
  for (int j = 0; j < 12; ++j) {
    int col = j * 64 + c8 * 8;
    f32x4 a = __builtin_nontemporal_load((const f32x4*)(xr + col));
    f32x4 b = __builtin_nontemporal_load((const f32x4*)(xr + col + 4));
    *(f16x8*)(hr + col) = cvt8(a, b);
  }
}

// K=512 main loop, ping-pong weight prefetch. actS pre-offset to wave's 64-row half.
template<int NF, int KSTEPS>
__device__ __forceinline__ void kloop_dp(
    const f16* __restrict__ actS, const f16* __restrict__ Wf, int fragRow0,
    int l16, int lhi, int lane, f32x4 (&acc)[4][4]) {
#pragma unroll
  for (int mi = 0; mi < 4; ++mi)
#pragma unroll
    for (int ni = 0; ni < NF; ++ni) acc[mi][ni] = (f32x4){0.f, 0.f, 0.f, 0.f};

  f16x8 bfU[NF], bfV[NF];
  const f16* wbase = Wf + ((size_t)fragRow0 * KSTEPS) * 512 + lane * 8;
#pragma unroll
  for (int ni = 0; ni < NF; ++ni)
    bfU[ni] = *(const f16x8*)(wbase + (size_t)(ni * KSTEPS + 0) * 512);
#pragma unroll
  for (int ni = 0; ni < NF; ++ni)
    bfV[ni] = *(const f16x8*)(wbase + (size_t)(ni * KSTEPS + 1) * 512);

#pragma unroll 1
  for (int ks = 0; ks < KSTEPS; ks += 2) {
    f16x8 af[4];
#pragma unroll
    for (int mi = 0; mi < 4; ++mi) {
      int r = mi * 16 + l16;
      af[mi] = *(const f16x8*)(actS + r * 512 + ((ks * 32 + lhi * 8) ^ ((r & 7) << 3)));
    }
#pragma unroll
    for (int mi = 0; mi < 4; ++mi)
#pragma unroll
      for (int ni = 0; ni < NF; ++ni)
        acc[mi][ni] = __builtin_amdgcn_mfma_f32_16x16x32_f16(bfU[ni], af[mi], acc[mi][ni], 0, 0, 0);
    if (ks + 2 < KSTEPS) {
#pragma unroll
      for (int ni = 0; ni < NF; ++ni)
        bfU[ni] = *(const f16x8*)(wbase + (size_t)(ni * KSTEPS + ks + 2) * 512);
    }
#pragma unroll
    for (int mi = 0; mi < 4; ++mi) {
      int r = mi * 16 + l16;
      af[mi] = *(const f16x8*)(actS + r * 512 + (((ks + 1) * 32 + lhi * 8) ^ ((r & 7) << 3)));
    }
#pragma unroll
    for (int mi = 0; mi < 4; ++mi)
#pragma unroll
      for (int ni = 0; ni < NF; ++ni)
        acc[mi][ni] = __builtin_amdgcn_mfma_f32_16x16x32_f16(bfV[ni], af[mi], acc[mi][ni], 0, 0, 0);
    if (ks + 3 < KSTEPS) {
#pragma unroll
      for (int ni = 0; ni < NF; ++ni)
        bfV[ni] = *(const f16x8*)(wbase + (size_t)(ni * KSTEPS + ks + 3) * 512);
    }
  }
}

// ---------------- fused MLP ----------------
// block = 128 rows, 16 waves (2 wr x 8 wc); wave tile 64 rows x 64 cols.
__global__ __launch_bounds__(1024, 4) void fused_mlp(
    const f16* __restrict__ H0,
    const f16* __restrict__ Wf0, const f16* __restrict__ Wf1,
    const f16* __restrict__ Wf2, const f16* __restrict__ Wf3,
    const float* __restrict__ b0, const float* __restrict__ b1,
    const float* __restrict__ b2, const float* __restrict__ b3,
    float* __restrict__ outp) {
  __shared__ f16 act[128 * 512];   // 128 KB, swizzled: r*512 + (c ^ ((r&7)<<3))
  f16* stg = act;                  // L0 staging alias: [2][128][64] f16 = 32 KB

  const int tid = threadIdx.x;
  const int wave = tid >> 6, lane = tid & 63;
  const int l16 = lane & 15, lhi = lane >> 4;
  const int wr = wave >> 3, wc = wave & 7;
  const int rowBase = blockIdx.x * 128;
  const int r = tid >> 3, c8 = tid & 7;   // staging: 8 threads/row, 16 B each

  // inverse-swizzled global source: LDS stays linear, read applies swizzle
  const f16* h0r = H0 + (size_t)(rowBase + r) * 832 + (size_t)((c8 ^ (r & 7)) * 8);
  f16* ldsA = stg + wave * 512;           // f16 units: wave*1024 B
  f16* ldsB = stg + 8192 + wave * 512;

  f32x4 acc[4][4];
#pragma unroll
  for (int mi = 0; mi < 4; ++mi)
#pragma unroll
    for (int ni = 0; ni < 4; ++ni) acc[mi][ni] = (f32x4){0.f, 0.f, 0.f, 0.f};

  // ================= Layer 0: K = 832 = 13 uniform steps x 64 =================
  {
    GLD16(h0r, ldsA);
    __syncthreads();
#pragma unroll 1
    for (int ks = 0; ks < 13; ++ks) {
      if (ks < 12) GLD16(h0r + (ks + 1) * 64, (ks & 1) ? ldsA : ldsB);
      f16x8 bf[2][4];
#pragma unroll
      for (int kk = 0; kk < 2; ++kk)
#pragma unroll
        for (int ni = 0; ni < 4; ++ni)
          bf[kk][ni] = *(const f16x8*)(Wf0 + (size_t)((wc * 4 + ni) * 26 + ks * 2 + kk) * 512 + lane * 8);
      const f16* rb = stg + (ks & 1) * 8192 + wr * 4096;   // wr*64 rows, 64 f16/row
#pragma unroll
      for (int kk = 0; kk < 2; ++kk)
#pragma unroll
        for (int mi = 0; mi < 4; ++mi) {
          int r2 = mi * 16 + l16;
          f16x8 af = *(const f16x8*)(rb + r2 * 64 + (((kk * 4 + lhi) ^ (r2 & 7)) << 3));
#pragma unroll
          for (int ni = 0; ni < 4; ++ni)
            acc[mi][ni] = __builtin_amdgcn_mfma_f32_16x16x32_f16(bf[kk][ni], af, acc[mi][ni], 0, 0, 0);
        }
      __syncthreads();
    }
  }

  // epilogue -> act (bias + silu). D-frag (swapped): row = wr*64 + mi*16 + l16,
  // cols = wc*64 + ni*16 + lhi*4 .. +3
  auto epi_act = [&](const float* __restrict__ bias) {
    __syncthreads();
#pragma unroll
    for (int mi = 0; mi < 4; ++mi) {
      const int row = wr * 64 + mi * 16 + l16;
#pragma unroll
      for (int ni = 0; ni < 4; ++ni) {
        const int col = wc * 64 + ni * 16 + lhi * 4;
        float4 bv = *(const float4*)(bias + col);
        f16x4 o;
        o[0] = (f16)silu_f(acc[mi][ni][0] + bv.x);
        o[1] = (f16)silu_f(acc[mi][ni][1] + bv.y);
        o[2] = (f16)silu_f(acc[mi][ni][2] + bv.z);
        o[3] = (f16)silu_f(acc[mi][ni][3] + bv.w);
        *(f16x4*)(act + row * 512 + (col ^ ((row & 7) << 3))) = o;
      }
    }
    __syncthreads();
  };
  epi_act(b0);

  const f16* actW = act + wr * 64 * 512;   // wave's 64-row half (row&7 preserved)

  // ================= Layers 1,2: K=512 =================
  kloop_dp<4, 16>(actW, Wf1, wc * 4, l16, lhi, lane, acc); epi_act(b1);
  kloop_dp<4, 16>(actW, Wf2, wc * 4, l16, lhi, lane, acc); epi_act(b2);

  // ================= Layer 3 pass A: cols 0..511 =================
  kloop_dp<4, 16>(actW, Wf3, wc * 4, l16, lhi, lane, acc);
#pragma unroll
  for (int mi = 0; mi < 4; ++mi) {
    const size_t row = (size_t)(rowBase + wr * 64 + mi * 16 + l16);
#pragma unroll
    for (int ni = 0; ni < 4; ++ni) {
      const int col = wc * 64 + ni * 16 + lhi * 4;
      float4 bv = *(const float4*)(b3 + col);
      f32x4 o = { acc[mi][ni][0] + bv.x, acc[mi][ni][1] + bv.y,
                  acc[mi][ni][2] + bv.z, acc[mi][ni][3] + bv.w };
      __builtin_nontemporal_store(o, (f32x4*)(outp + row * 768 + col));
    }
  }

  // ================= Layer 3 pass B: cols 512..767 =================
  kloop_dp<2, 16>(actW, Wf3, 32 + wc * 2, l16, lhi, lane, acc);
#pragma unroll
  for (int mi = 0; mi < 4; ++mi) {
    const size_t row = (size_t)(rowBase + wr * 64 + mi * 16 + l16);
#pragma unroll
    for (int ni = 0; ni < 2; ++ni) {
      const int col = 512 + wc * 32 + ni * 16 + lhi * 4;
      float4 bv = *(const float4*)(b3 + col);
      f32x4 o = { acc[mi][ni][0] + bv.x, acc[mi][ni][1] + bv.y,
                  acc[mi][ni][2] + bv.z, acc[mi][ni][3] + bv.w };
      __builtin_nontemporal_store(o, (f32x4*)(outp + row * 768 + col));
    }
  }
}

// ---------------- launch ----------------
extern "C" void kernel_launch(void* const* d_in, const int* in_sizes, int n_in,
                              void* d_out, int out_size, void* d_ws, size_t ws_size,
                              hipStream_t stream) {
  const float* t    = (const float*)d_in[0];
  const float* x    = (const float*)d_in[1];
  const float* cond = (const float*)d_in[2];
  const float* tab  = (const float*)d_in[3];
  const float* W0   = (const float*)d_in[4];
  const float* b0   = (const float*)d_in[5];
  const float* W1   = (const float*)d_in[6];
  const float* b1   = (const float*)d_in[7];
  const float* W2   = (const float*)d_in[8];
  const float* b2   = (const float*)d_in[9];
  const float* W3   = (const float*)d_in[10];
  const float* b3   = (const float*)d_in[11];
  float* out = (float*)d_out;
  (void)in_sizes; (void)n_in; (void)out_size; (void)ws_size;

  char* ws = (char*)d_ws;
  f16* Wf0 = (f16*)(ws + 0);            // 832*512*2 = 851968
  f16* Wf1 = (f16*)(ws + 851968);       // 524288
  f16* Wf2 = (f16*)(ws + 1376256);      // 524288
  f16* Wf3 = (f16*)(ws + 1900544);      // 786432 ; end 2686976
  f16* H0  = (f16*)(ws + 2686976);      // 65536*832*2 = 109051904

  wfrag<<<dim3(208), 256, 0, stream>>>(W0, Wf0, 832, 512);
  wfrag<<<dim3(128), 256, 0, stream>>>(W1, Wf1, 512, 512);
  wfrag<<<dim3(128), 256, 0, stream>>>(W2, Wf2, 512, 512);
  wfrag<<<dim3(192), 256, 0, stream>>>(W3, Wf3, 512, 768);

  Scales sc;
  {
    double growth = exp((log(512.0) - log(16.0)) / 15.0);
    for (int l = 0; l < 16; ++l) sc.s[l] = (float)floor(16.0 * pow(growth, (double)l));
  }

  prep<<<dim3(2048), 256, 0, stream>>>(x, t, cond, tab, H0, sc);

  fused_mlp<<<dim3(512), 1024, 0, stream>>>(H0, Wf0, Wf1, Wf2, Wf3,
                                            b0, b1, b2, b3, out);
}

// Round 13
// 299.171 us; speedup vs baseline: 1.1642x; 1.1642x over previous
//
#include <hip/hip_runtime.h>
#include <hip/hip_bf16.h>
#include <math.h>

// v13: fully-fused, 64-row / 8-wave blocks (2 blocks/CU), enc in-kernel.
// L0 = 12 x BK64 steps staging x fp32 via global_load_lds, 3-buffer rotation,
// counted vmcnt(10/8) + raw s_barrier AFTER the wait and BEFORE consume
// (fixes v12's race: barrier orders all waves' stages; 3 bufs keep the
// written buffer disjoint from any concurrently-readable one).
// v12's half-1 source offset bug fixed: +32 floats (was +8).

#define T_SIZE 524288   // 2^19
#define T_MASK (T_SIZE - 1)

typedef _Float16 f16;
typedef _Float16 f16x8 __attribute__((ext_vector_type(8)));
typedef _Float16 f16x4 __attribute__((ext_vector_type(4)));
typedef float f32x4 __attribute__((ext_vector_type(4)));

struct Scales { float s[16]; };

#define GLD16(gsrc, ldst) __builtin_amdgcn_global_load_lds( \
    (const __attribute__((address_space(1))) void*)(gsrc),  \
    (__attribute__((address_space(3))) void*)(ldst), 16, 0, 0)
#define SB() __builtin_amdgcn_sched_barrier(0)

// ---------------- weight -> fragment-linear f16 ----------------
// Wf[frag][lane][8]: frag = nblk*(K/32)+ks32; (lane,j) = W[ks32*32+(lane>>4)*8+j][nblk*16+(lane&15)]
__global__ void wfrag(const float* __restrict__ W, f16* __restrict__ Wf, int K, int N) {
  int tid = blockIdx.x * 256 + threadIdx.x;
  int lane = tid & 63, frag = tid >> 6;
  int KS = K >> 5;
  int nblk = frag / KS, ks = frag - nblk * KS;
  if (nblk * 16 >= N) return;
  int n = nblk * 16 + (lane & 15);
  int kb = ks * 32 + (lane >> 4) * 8;
  f16x8 v;
#pragma unroll
  for (int j = 0; j < 8; ++j) v[j] = (f16)W[(size_t)(kb + j) * N + n];
  *(f16x8*)(Wf + (size_t)frag * 512 + lane * 8) = v;
}

__device__ __forceinline__ float silu_f(float v) {
  return v * __builtin_amdgcn_rcpf(1.f + __expf(-v));
}

__device__ __forceinline__ f16x8 cvt8(f32x4 a, f32x4 b) {
  return (f16x8){ (f16)a.x, (f16)a.y, (f16)a.z, (f16)a.w,
                  (f16)b.x, (f16)b.y, (f16)b.z, (f16)b.w };
}

// K=512 main loop, ping-pong weight prefetch (v10-proven).
template<int NF, int KSTEPS>
__device__ __forceinline__ void kloop_dp(
    const f16* __restrict__ actS, const f16* __restrict__ Wf, int fragRow0,
    int l16, int lhi, int lane, f32x4 (&acc)[4][4]) {
#pragma unroll
  for (int mi = 0; mi < 4; ++mi)
#pragma unroll
    for (int ni = 0; ni < NF; ++ni) acc[mi][ni] = (f32x4){0.f, 0.f, 0.f, 0.f};

  f16x8 bfU[NF], bfV[NF];
  const f16* wbase = Wf + ((size_t)fragRow0 * KSTEPS) * 512 + lane * 8;
#pragma unroll
  for (int ni = 0; ni < NF; ++ni)
    bfU[ni] = *(const f16x8*)(wbase + (size_t)(ni * KSTEPS + 0) * 512);
#pragma unroll
  for (int ni = 0; ni < NF; ++ni)
    bfV[ni] = *(const f16x8*)(wbase + (size_t)(ni * KSTEPS + 1) * 512);

#pragma unroll 1
  for (int ks = 0; ks < KSTEPS; ks += 2) {
    f16x8 af[4];
#pragma unroll
    for (int mi = 0; mi < 4; ++mi) {
      int r = mi * 16 + l16;
      af[mi] = *(const f16x8*)(actS + r * 512 + ((ks * 32 + lhi * 8) ^ ((r & 7) << 3)));
    }
#pragma unroll
    for (int mi = 0; mi < 4; ++mi)
#pragma unroll
      for (int ni = 0; ni < NF; ++ni)
        acc[mi][ni] = __builtin_amdgcn_mfma_f32_16x16x32_f16(bfU[ni], af[mi], acc[mi][ni], 0, 0, 0);
    if (ks + 2 < KSTEPS) {
#pragma unroll
      for (int ni = 0; ni < NF; ++ni)
        bfU[ni] = *(const f16x8*)(wbase + (size_t)(ni * KSTEPS + ks + 2) * 512);
    }
#pragma unroll
    for (int mi = 0; mi < 4; ++mi) {
      int r = mi * 16 + l16;
      af[mi] = *(const f16x8*)(actS + r * 512 + (((ks + 1) * 32 + lhi * 8) ^ ((r & 7) << 3)));
    }
#pragma unroll
    for (int mi = 0; mi < 4; ++mi)
#pragma unroll
      for (int ni = 0; ni < NF; ++ni)
        acc[mi][ni] = __builtin_amdgcn_mfma_f32_16x16x32_f16(bfV[ni], af[mi], acc[mi][ni], 0, 0, 0);
    if (ks + 3 < KSTEPS) {
#pragma unroll
      for (int ni = 0; ni < NF; ++ni)
        bfV[ni] = *(const f16x8*)(wbase + (size_t)(ni * KSTEPS + ks + 3) * 512);
    }
  }
}

// ---------------- fused MLP ----------------
// block = 64 rows, 8 waves; wave w owns cols [64w, 64w+64).
__global__ __launch_bounds__(512, 4) void fused_mlp(
    const float* __restrict__ x, const float* __restrict__ t,
    const float* __restrict__ cond, const float* __restrict__ tables,
    const f16* __restrict__ Wf0, const f16* __restrict__ Wf1,
    const f16* __restrict__ Wf2, const f16* __restrict__ Wf3,
    const float* __restrict__ b0, const float* __restrict__ b1,
    const float* __restrict__ b2, const float* __restrict__ b3,
    float* __restrict__ outp, Scales scl) {
  __shared__ f16 act[64 * 512];   // 64 KB, swizzled: r*512 + (c ^ ((r&7)<<3))
  __shared__ f16 encs[64 * 64];   // 8 KB enc buffer, swizzled 16B chunks
  // L0 fp32 staging ALIASED into act: buf p (p=0,1,2) at p*16384;
  // within: half kk at kk*8192, row r at r*128, chunk c at c*16.
  char* stg = (char*)act;

  const int tid = threadIdx.x;
  const int wave = tid >> 6, lane = tid & 63;
  const int l16 = lane & 15, lhi = lane >> 4;
  const int rowBase = blockIdx.x * 64;
  const int sr = tid >> 3, c8 = tid & 7;   // 8 threads/row

  // ---- hash-grid encode: thread (sr,c8) -> levels 2c8, 2c8+1 of row sr ----
  {
    int row = rowBase + sr;
    float c0 = cond[2 * row], c1 = cond[2 * row + 1], c2 = t[row];
    unsigned idx[2][8];
    float    wcw[2][8];
#pragma unroll
    for (int d = 0; d < 2; ++d) {
      int l = c8 * 2 + d;
      float s = scl.s[l];
      float xf0 = c0 * s, xf1 = c1 * s, xf2 = c2 * s;
      float xl0 = floorf(xf0), xl1 = floorf(xf1), xl2 = floorf(xf2);
      float w0 = xf0 - xl0, w1 = xf1 - xl1, w2 = xf2 - xl2;
      unsigned xi0 = (unsigned)xl0, xi1 = (unsigned)xl1, xi2 = (unsigned)xl2;
      unsigned h0 = xi0, h1 = xi1 * 2654435761u, h2 = xi2 * 805459861u;
      unsigned g0 = xi0 + 1u, g1 = (xi1 + 1u) * 2654435761u, g2 = (xi2 + 1u) * 805459861u;
#pragma unroll
      for (int c = 0; c < 8; ++c) {
        unsigned ax = (c >> 2) & 1u, ay = (c >> 1) & 1u, az = c & 1u;
        unsigned hh = (ax ? g0 : h0) ^ (ay ? g1 : h1) ^ (az ? g2 : h2);
        idx[d][c] = hh & T_MASK;
        wcw[d][c] = (ax ? w0 : 1.f - w0) * (ay ? w1 : 1.f - w1) * (az ? w2 : 1.f - w2);
      }
    }
    const f32x4* tl0 = (const f32x4*)tables + (size_t)(c8 * 2) * T_SIZE;
    f32x4 fv[2][8];
#pragma unroll
    for (int d = 0; d < 2; ++d)
#pragma unroll
      for (int c = 0; c < 8; ++c)
        fv[d][c] = tl0[(size_t)d * T_SIZE + idx[d][c]];
    f16x8 er;
#pragma unroll
    for (int d = 0; d < 2; ++d) {
      float a0 = 0.f, a1 = 0.f, a2 = 0.f, a3 = 0.f;
#pragma unroll
      for (int c = 0; c < 8; ++c) {
        a0 += wcw[d][c] * fv[d][c].x; a1 += wcw[d][c] * fv[d][c].y;
        a2 += wcw[d][c] * fv[d][c].z; a3 += wcw[d][c] * fv[d][c].w;
      }
      er[d * 4 + 0] = (f16)a0; er[d * 4 + 1] = (f16)a1;
      er[d * 4 + 2] = (f16)a2; er[d * 4 + 3] = (f16)a3;
    }
    // LDS chunk c8^(sr&7) holds global enc chunk c8 of row sr
    *(f16x8*)(encs + sr * 64 + ((c8 ^ (sr & 7)) * 8)) = er;
  }

  f32x4 acc[4][4];
#pragma unroll
  for (int mi = 0; mi < 4; ++mi)
#pragma unroll
    for (int ni = 0; ni < 4; ++ni) acc[mi][ni] = (f32x4){0.f, 0.f, 0.f, 0.f};

  // ================= Layer 0: 12 x BK64 fp32 steps + enc step ================
  {
    // inverse-swizzled source: LDS chunk c8 of (row, half) holds global chunk c8^(sr&7)
    const float* xsrc = x + (size_t)(rowBase + sr) * 768 + (size_t)((c8 ^ (sr & 7)) * 4);

    // prologue: stage step 0 into buf 0 (halves at +0 / +32 floats)
    GLD16(xsrc,      stg + wave * 1024);
    GLD16(xsrc + 32, stg + 8192 + wave * 1024);
    __syncthreads();   // drains stage 0, publishes encs

    int pr = 0, pw = 1;   // read / write buffer indices (mod 3)
#pragma unroll 1
    for (int s = 0; s < 12; ++s) {
      // --- issue stage s+1 into buf pw (distinct from any readable buf) ---
      if (s < 11) {
        GLD16(xsrc + (s + 1) * 64,      stg + pw * 16384 + wave * 1024);
        GLD16(xsrc + (s + 1) * 64 + 32, stg + pw * 16384 + 8192 + wave * 1024);
      }
      SB();
      // --- weight frags for step s ---
      f16x8 bf[2][4];
#pragma unroll
      for (int kk = 0; kk < 2; ++kk)
#pragma unroll
        for (int ni = 0; ni < 4; ++ni)
          bf[kk][ni] = *(const f16x8*)(Wf0 + (size_t)((wave * 4 + ni) * 26 + 2 * s + kk) * 512 + lane * 8);
      SB();
      // --- counted wait: retire exactly stage s (oldest 2 of 12 / 10) ---
      if (s < 11) asm volatile("s_waitcnt vmcnt(10)" ::: "memory");
      else        asm volatile("s_waitcnt vmcnt(8)"  ::: "memory");
      SB();
      __builtin_amdgcn_s_barrier();   // all waves' stage s now visible
      SB();
      // --- consume stage s from buf pr ---
      const char* rb = stg + pr * 16384;
      __builtin_amdgcn_s_setprio(1);
#pragma unroll
      for (int kk = 0; kk < 2; ++kk)
#pragma unroll
        for (int mi = 0; mi < 4; ++mi) {
          int r2 = mi * 16 + l16;
          const char* rowb = rb + kk * 8192 + r2 * 128;
          f32x4 a = *(const f32x4*)(rowb + (((lhi * 2)     ^ (r2 & 7)) << 4));
          f32x4 b = *(const f32x4*)(rowb + (((lhi * 2 + 1) ^ (r2 & 7)) << 4));
          f16x8 af = cvt8(a, b);
#pragma unroll
          for (int ni = 0; ni < 4; ++ni)
            acc[mi][ni] = __builtin_amdgcn_mfma_f32_16x16x32_f16(bf[kk][ni], af, acc[mi][ni], 0, 0, 0);
        }
      __builtin_amdgcn_s_setprio(0);
      SB();
      pr = (pr == 2) ? 0 : pr + 1;
      pw = (pw == 2) ? 0 : pw + 1;
    }

    // step 12: enc fragments from encs (stable since prologue barrier)
    {
      f16x8 bf[2][4];
#pragma unroll
      for (int kk = 0; kk < 2; ++kk)
#pragma unroll
        for (int ni = 0; ni < 4; ++ni)
          bf[kk][ni] = *(const f16x8*)(Wf0 + (size_t)((wave * 4 + ni) * 26 + 24 + kk) * 512 + lane * 8);
#pragma unroll
      for (int kk = 0; kk < 2; ++kk)
#pragma unroll
        for (int mi = 0; mi < 4; ++mi) {
          int r2 = mi * 16 + l16;
          f16x8 af = *(const f16x8*)(encs + r2 * 64 + (((kk * 4 + lhi) ^ (r2 & 7)) * 8));
#pragma unroll
          for (int ni = 0; ni < 4; ++ni)
            acc[mi][ni] = __builtin_amdgcn_mfma_f32_16x16x32_f16(bf[kk][ni], af, acc[mi][ni], 0, 0, 0);
        }
    }
  }

  // epilogue -> act (bias + silu). D-frag (swapped): act-row = mi*16+l16,
  // cols = wave*64 + ni*16 + lhi*4 .. +3
  auto epi_act = [&](const float* __restrict__ bias) {
    __syncthreads();
#pragma unroll
    for (int mi = 0; mi < 4; ++mi) {
      const int row = mi * 16 + l16;
#pragma unroll
      for (int ni = 0; ni < 4; ++ni) {
        const int col = wave * 64 + ni * 16 + lhi * 4;
        float4 bv = *(const float4*)(bias + col);
        f16x4 o;
        o[0] = (f16)silu_f(acc[mi][ni][0] + bv.x);
        o[1] = (f16)silu_f(acc[mi][ni][1] + bv.y);
        o[2] = (f16)silu_f(acc[mi][ni][2] + bv.z);
        o[3] = (f16)silu_f(acc[mi][ni][3] + bv.w);
        *(f16x4*)(act + row * 512 + (col ^ ((row & 7) << 3))) = o;
      }
    }
    __syncthreads();
  };
  epi_act(b0);

  // ================= Layers 1,2: K=512 =================
  kloop_dp<4, 16>(act, Wf1, wave * 4, l16, lhi, lane, acc); epi_act(b1);
  kloop_dp<4, 16>(act, Wf2, wave * 4, l16, lhi, lane, acc); epi_act(b2);

  // ================= Layer 3 pass A: cols 0..511 =================
  kloop_dp<4, 16>(act, Wf3, wave * 4, l16, lhi, lane, acc);
#pragma unroll
  for (int mi = 0; mi < 4; ++mi) {
    const size_t row = (size_t)(rowBase + mi * 16 + l16);
#pragma unroll
    for (int ni = 0; ni < 4; ++ni) {
      const int col = wave * 64 + ni * 16 + lhi * 4;
      float4 bv = *(const float4*)(b3 + col);
      f32x4 o = { acc[mi][ni][0] + bv.x, acc[mi][ni][1] + bv.y,
                  acc[mi][ni][2] + bv.z, acc[mi][ni][3] + bv.w };
      __builtin_nontemporal_store(o, (f32x4*)(outp + row * 768 + col));
    }
  }

  // ================= Layer 3 pass B: cols 512..767 =================
  kloop_dp<2, 16>(act, Wf3, 32 + wave * 2, l16, lhi, lane, acc);
#pragma unroll
  for (int mi = 0; mi < 4; ++mi) {
    const size_t row = (size_t)(rowBase + mi * 16 + l16);
#pragma unroll
    for (int ni = 0; ni < 2; ++ni) {
      const int col = 512 + wave * 32 + ni * 16 + lhi * 4;
      float4 bv = *(const float4*)(b3 + col);
      f32x4 o = { acc[mi][ni][0] + bv.x, acc[mi][ni][1] + bv.y,
                  acc[mi][ni][2] + bv.z, acc[mi][ni][3] + bv.w };
      __builtin_nontemporal_store(o, (f32x4*)(outp + row * 768 + col));
    }
  }
}

// ---------------- launch ----------------
extern "C" void kernel_launch(void* const* d_in, const int* in_sizes, int n_in,
                              void* d_out, int out_size, void* d_ws, size_t ws_size,
                              hipStream_t stream) {
  const float* t    = (const float*)d_in[0];
  const float* x    = (const float*)d_in[1];
  const float* cond = (const float*)d_in[2];
  const float* tab  = (const float*)d_in[3];
  const float* W0   = (const float*)d_in[4];
  const float* b0   = (const float*)d_in[5];
  const float* W1   = (const float*)d_in[6];
  const float* b1   = (const float*)d_in[7];
  const float* W2   = (const float*)d_in[8];
  const float* b2   = (const float*)d_in[9];
  const float* W3   = (const float*)d_in[10];
  const float* b3   = (const float*)d_in[11];
  float* out = (float*)d_out;
  (void)in_sizes; (void)n_in; (void)out_size; (void)ws_size;

  char* ws = (char*)d_ws;
  f16* Wf0 = (f16*)(ws + 0);            // 832*512*2 = 851968
  f16* Wf1 = (f16*)(ws + 851968);       // 524288
  f16* Wf2 = (f16*)(ws + 1376256);      // 524288
  f16* Wf3 = (f16*)(ws + 1900544);      // 786432 ; end 2686976

  wfrag<<<dim3(208), 256, 0, stream>>>(W0, Wf0, 832, 512);
  wfrag<<<dim3(128), 256, 0, stream>>>(W1, Wf1, 512, 512);
  wfrag<<<dim3(128), 256, 0, stream>>>(W2, Wf2, 512, 512);
  wfrag<<<dim3(192), 256, 0, stream>>>(W3, Wf3, 512, 768);

  Scales sc;
  {
    double growth = exp((log(512.0) - log(16.0)) / 15.0);
    for (int l = 0; l < 16; ++l) sc.s[l] = (float)floor(16.0 * pow(growth, (double)l));
  }

  fused_mlp<<<dim3(1024), 512, 0, stream>>>(x, t, cond, tab, Wf0, Wf1, Wf2, Wf3,
                                            b0, b1, b2, b3, out, sc);
}